// Round 2
// baseline (277.220 us; speedup 1.0000x reference)
//
#include <hip/hip_runtime.h>

typedef float f32x4 __attribute__((ext_vector_type(4)));
typedef __bf16 bf16x8_t __attribute__((ext_vector_type(8)));
typedef __bf16 bf16x4_t __attribute__((ext_vector_type(4)));

#define GLOAD16(gptr, lptr)                                                        \
  __builtin_amdgcn_global_load_lds((const __attribute__((address_space(1))) void*)(gptr), \
                                   (__attribute__((address_space(3))) void*)(lptr), 16, 0, 0)

__device__ inline float fexp2(float x) {
  float r;
  asm("v_exp_f32 %0, %1" : "=v"(r) : "v"(x));
  return r;
}

// ---------------- prep kernels ----------------

__global__ __launch_bounds__(256) void k_cvt_x(const float* __restrict__ x,
                                               __bf16* __restrict__ xb, int n4) {
  int i = blockIdx.x * 256 + threadIdx.x;
  if (i >= n4) return;
  float4 a = reinterpret_cast<const float4*>(x)[i];
  bf16x4_t o;
  o[0] = (__bf16)a.x; o[1] = (__bf16)a.y; o[2] = (__bf16)a.z; o[3] = (__bf16)a.w;
  reinterpret_cast<bf16x4_t*>(xb)[i] = o;
}

// W_p[h][d][e] (fp32, [16][1024][64]) -> WB1[(p*1024 + h*64 + e)][d] bf16
__global__ __launch_bounds__(256) void k_packw1(const float* __restrict__ wq,
                                                const float* __restrict__ wk,
                                                const float* __restrict__ wv,
                                                __bf16* __restrict__ out) {
  __shared__ __bf16 tr[64][64];  // [e][dd]
  int p = blockIdx.z, h = blockIdx.y, dt = blockIdx.x;
  const float* W = (p == 0) ? wq : (p == 1) ? wk : wv;
  int t = threadIdx.x;
#pragma unroll
  for (int i = 0; i < 4; ++i) {
    int fl = i * 1024 + t * 4;    // d-major over 64x64 tile
    int dd = fl >> 6, e = fl & 63;
    float4 a = *reinterpret_cast<const float4*>(W + ((size_t)(h * 1024 + dt * 64 + dd) * 64 + e));
    tr[e + 0][dd] = (__bf16)a.x; tr[e + 1][dd] = (__bf16)a.y;
    tr[e + 2][dd] = (__bf16)a.z; tr[e + 3][dd] = (__bf16)a.w;
  }
  __syncthreads();
#pragma unroll
  for (int i = 0; i < 2; ++i) {
    int ch = i * 256 + t;         // 512 chunks of 8 elems
    int e = ch >> 3, c8 = ch & 7;
    *reinterpret_cast<bf16x8_t*>(out + ((size_t)(p * 1024 + h * 64 + e) * 1024 + dt * 64 + c8 * 8)) =
        *reinterpret_cast<const bf16x8_t*>(&tr[e][c8 * 8]);
  }
}

// W_O[h][e][n] (fp32, [16][64][1024]) -> WB2[n][h*64 + e] bf16
__global__ __launch_bounds__(256) void k_packw2(const float* __restrict__ wo,
                                                __bf16* __restrict__ out) {
  __shared__ __bf16 tr[64][64];  // [nn][e]
  int h = blockIdx.y, nt = blockIdx.x;
  int t = threadIdx.x;
#pragma unroll
  for (int i = 0; i < 4; ++i) {
    int fl = i * 1024 + t * 4;    // e-major
    int e = fl >> 6, nn = fl & 63;
    float4 a = *reinterpret_cast<const float4*>(wo + ((size_t)(h * 64 + e) * 1024 + nt * 64 + nn));
    tr[nn + 0][e] = (__bf16)a.x; tr[nn + 1][e] = (__bf16)a.y;
    tr[nn + 2][e] = (__bf16)a.z; tr[nn + 3][e] = (__bf16)a.w;
  }
  __syncthreads();
#pragma unroll
  for (int i = 0; i < 2; ++i) {
    int ch = i * 256 + t;
    int nn = ch >> 3, c8 = ch & 7;
    *reinterpret_cast<bf16x8_t*>(out + ((size_t)(nt * 64 + nn) * 1024 + h * 64 + c8 * 8)) =
        *reinterpret_cast<const bf16x8_t*>(&tr[nn][c8 * 8]);
  }
}

__global__ __launch_bounds__(256) void k_bias1(const float* __restrict__ bq,
                                               const float* __restrict__ bk,
                                               const float* __restrict__ bv,
                                               float* __restrict__ b1) {
  int n = blockIdx.x * 256 + threadIdx.x;
  if (n >= 3072) return;
  int p = n >> 10, he = n & 1023;
  const float* s = (p == 0) ? bq : (p == 1) ? bk : bv;
  b1[n] = s[he];
}

// ---------------- GEMM: C[M][N] = A[M][K] * Bt[N][K]^T + bias[N] ----------------
template <typename OutT>
__global__ __launch_bounds__(256) void k_gemm(const __bf16* __restrict__ A,
                                              const __bf16* __restrict__ Bt,
                                              const float* __restrict__ bias,
                                              OutT* __restrict__ C, int N, int K) {
  __shared__ __bf16 As[128 * 32];
  __shared__ __bf16 Bs[128 * 32];
  int t = threadIdx.x, l = t & 63;
  int lo = l & 15, hi = l >> 4;
  int w = t >> 6;
  int m0 = blockIdx.y * 128, n0 = blockIdx.x * 128;
  int wm = (w >> 1) * 64, wn = (w & 1) * 64;
  f32x4 acc[4][4] = {};
  for (int k0 = 0; k0 < K; k0 += 32) {
    __syncthreads();
#pragma unroll
    for (int it = 0; it < 2; ++it) {
      int idx = it * 256 + t;
      int row = idx >> 2, c = idx & 3;
      int cs = (c ^ (row & 3)) * 8;
      const __bf16* ga = A + (size_t)(m0 + row) * K + k0 + cs;
      const __bf16* gb = Bt + (size_t)(n0 + row) * K + k0 + cs;
      char* la = (char*)As + (it * 256 + (t & ~63)) * 16;
      char* lb = (char*)Bs + (it * 256 + (t & ~63)) * 16;
      GLOAD16(ga, la);
      GLOAD16(gb, lb);
    }
    __syncthreads();
    bf16x8_t af[4], bfr[4];
#pragma unroll
    for (int mi = 0; mi < 4; ++mi) {
      int row = wm + mi * 16 + lo;
      af[mi] = *reinterpret_cast<const bf16x8_t*>((char*)As + row * 64 + ((hi ^ (row & 3)) << 4));
    }
#pragma unroll
    for (int ni = 0; ni < 4; ++ni) {
      int row = wn + ni * 16 + lo;
      bfr[ni] = *reinterpret_cast<const bf16x8_t*>((char*)Bs + row * 64 + ((hi ^ (row & 3)) << 4));
    }
#pragma unroll
    for (int mi = 0; mi < 4; ++mi)
#pragma unroll
      for (int ni = 0; ni < 4; ++ni)
        acc[mi][ni] = __builtin_amdgcn_mfma_f32_16x16x32_bf16(af[mi], bfr[ni], acc[mi][ni], 0, 0, 0);
  }
#pragma unroll
  for (int ni = 0; ni < 4; ++ni) {
    int n = n0 + wn + ni * 16 + lo;
    float bv = bias[n];
#pragma unroll
    for (int mi = 0; mi < 4; ++mi) {
#pragma unroll
      for (int r = 0; r < 4; ++r) {
        int m = m0 + wm + mi * 16 + hi * 4 + r;
        C[(size_t)m * N + n] = (OutT)(acc[mi][ni][r] + bv);
      }
    }
  }
}

// ---------------- causal flash attention (v2) ----------------
// QKV [4096][3072] bf16 (Q at 0, K at 1024, V at 2048; col = h*64+e).
// QBLK=128 (4 waves x 32 rows), KVBLK=64, double-buffered K/V, 1 barrier/tile.
__global__ __launch_bounds__(256, 3) void k_attn(const __bf16* __restrict__ QKV,
                                                 __bf16* __restrict__ Z) {
  __shared__ __bf16 Ks[2][64 * 64];  // row-swizzled: chunk ^= row&7
  __shared__ __bf16 Vt[2][64 * 64];  // [e][kv], chunk ^= ((e>>3)^e)&7 ^ ...
  __shared__ __bf16 Ps[128 * 64];    // row-swizzled, wave-private rows
  int t = threadIdx.x, l = t & 63, w = t >> 6;
  int lo = l & 15, hi = l >> 4;
  int bh = blockIdx.y, b = bh >> 4, h = bh & 15;
  int q0 = (int)(gridDim.x - 1 - blockIdx.x) * 128;  // long blocks first
  const size_t rowQ = (size_t)(b * 2048 + q0 + w * 32);

  const __bf16* Kbase = QKV + (size_t)b * 2048 * 3072 + 1024 + h * 64;
  const __bf16* Vbase = QKV + (size_t)b * 2048 * 3072 + 2048 + h * 64;

  // Q fragments: 2 m-blocks x 2 k-chunks
  bf16x8_t qf[2][2];
#pragma unroll
  for (int m = 0; m < 2; ++m) {
    const __bf16* qptr = QKV + (rowQ + m * 16 + lo) * 3072 + h * 64;
    qf[m][0] = *reinterpret_cast<const bf16x8_t*>(qptr + hi * 8);
    qf[m][1] = *reinterpret_cast<const bf16x8_t*>(qptr + 32 + hi * 8);
  }

  // ones B-fragment (col 0 = 1) for row-sum via MFMA
  bf16x8_t vones;
  {
    __bf16 v1 = (__bf16)((lo == 0) ? 1.0f : 0.0f);
#pragma unroll
    for (int j = 0; j < 8; ++j) vones[j] = v1;
  }

  f32x4 zacc[2][4] = {};
  f32x4 lsum[2] = {};
  float mrow[2][4];
#pragma unroll
  for (int m = 0; m < 2; ++m)
#pragma unroll
    for (int r = 0; r < 4; ++r) mrow[m][r] = -1e30f;

  int nt = q0 / 64 + 2;
  bf16x8_t vr[2];

#define STAGE_K(buf, tile)                                                              \
  {                                                                                     \
    int kv0s = (tile) * 64;                                                             \
    _Pragma("unroll") for (int it = 0; it < 2; ++it) {                                  \
      int idx = it * 256 + t;                                                           \
      int row = idx >> 3, c = idx & 7;                                                  \
      const __bf16* gk = Kbase + (size_t)(kv0s + row) * 3072 + ((c ^ (row & 7)) * 8);   \
      GLOAD16(gk, (char*)Ks[buf] + (it * 256 + (t & ~63)) * 16);                        \
    }                                                                                   \
  }

#define LOAD_V(tile)                                                                    \
  {                                                                                     \
    _Pragma("unroll") for (int it = 0; it < 2; ++it) {                                  \
      int idx = it * 256 + t;                                                           \
      int kv = idx >> 3, c = idx & 7;                                                   \
      vr[it] = *reinterpret_cast<const bf16x8_t*>(                                      \
          Vbase + (size_t)((tile) * 64 + kv) * 3072 + c * 8);                           \
    }                                                                                   \
  }

#define WRITE_V(buf)                                                                    \
  {                                                                                     \
    _Pragma("unroll") for (int it = 0; it < 2; ++it) {                                  \
      int idx = it * 256 + t;                                                           \
      int kv = idx >> 3, c = idx & 7, kvc = kv >> 3, kvl = kv & 7;                      \
      _Pragma("unroll") for (int j = 0; j < 8; ++j) {                                   \
        int e = c * 8 + j;                                                              \
        *(__bf16*)((char*)Vt[buf] + e * 128 + (((kvc ^ c ^ j) & 7) << 4) + kvl * 2) =   \
            vr[it][j];                                                                  \
      }                                                                                 \
    }                                                                                   \
  }

  // prologue: stage tile 0 into buffer 0
  STAGE_K(0, 0);
  LOAD_V(0);
  asm volatile("s_waitcnt vmcnt(0)" ::: "memory");
  WRITE_V(0);
  __syncthreads();

  for (int tile = 0; tile < nt; ++tile) {
    int cur = tile & 1, kv0 = tile * 64;
    bool last = (tile == nt - 1);
    if (!last) {
      STAGE_K(cur ^ 1, tile + 1);
      LOAD_V(tile + 1);
    }
    // QK^T: sfr[m][cb], D[row=q(hi*4+r)][col=kv(lo)]
    f32x4 sfr[2][4] = {};
#pragma unroll
    for (int cb = 0; cb < 4; ++cb) {
      int krow = cb * 16 + lo;
      const char* kp = (const char*)Ks[cur] + krow * 128;
      bf16x8_t kf0 = *reinterpret_cast<const bf16x8_t*>(kp + ((hi ^ (krow & 7)) << 4));
      bf16x8_t kf1 = *reinterpret_cast<const bf16x8_t*>(kp + (((4 + hi) ^ (krow & 7)) << 4));
#pragma unroll
      for (int m = 0; m < 2; ++m) {
        sfr[m][cb] = __builtin_amdgcn_mfma_f32_16x16x32_bf16(qf[m][0], kf0, sfr[m][cb], 0, 0, 0);
        sfr[m][cb] = __builtin_amdgcn_mfma_f32_16x16x32_bf16(qf[m][1], kf1, sfr[m][cb], 0, 0, 0);
      }
    }
    // softmax (exp2 domain; scale = 0.125*log2(e))
#pragma unroll
    for (int m = 0; m < 2; ++m) {
      int qb = q0 + w * 32 + m * 16;
      bool msk = (kv0 + 63) > qb;
      float mt[4] = {-1e30f, -1e30f, -1e30f, -1e30f};
#pragma unroll
      for (int cb = 0; cb < 4; ++cb) {
#pragma unroll
        for (int r = 0; r < 4; ++r) {
          float v = sfr[m][cb][r] * 0.18033688f;
          if (msk && (kv0 + cb * 16 + lo > qb + hi * 4 + r)) v = -1e30f;
          sfr[m][cb][r] = v;
          mt[r] = fmaxf(mt[r], v);
        }
      }
#pragma unroll
      for (int r = 0; r < 4; ++r) {
        mt[r] = fmaxf(mt[r], __shfl_xor(mt[r], 8));
        mt[r] = fmaxf(mt[r], __shfl_xor(mt[r], 4));
        mt[r] = fmaxf(mt[r], __shfl_xor(mt[r], 2));
        mt[r] = fmaxf(mt[r], __shfl_xor(mt[r], 1));
        float mnew = fmaxf(mrow[m][r], mt[r]);
        float alpha = fexp2(mrow[m][r] - mnew);
        mrow[m][r] = mnew;
        lsum[m][r] *= alpha;
#pragma unroll
        for (int e0 = 0; e0 < 4; ++e0) zacc[m][e0][r] *= alpha;
      }
      // P = exp2(s - m) -> Ps (bf16, swizzled; wave-private rows)
#pragma unroll
      for (int cb = 0; cb < 4; ++cb) {
        int kvl = cb * 16 + lo, chp = kvl >> 3, wi = kvl & 7;
#pragma unroll
        for (int r = 0; r < 4; ++r) {
          float p = fexp2(sfr[m][cb][r] - mrow[m][r]);
          int prow = w * 32 + m * 16 + hi * 4 + r;
          *(__bf16*)((char*)Ps + prow * 128 + (((chp ^ (prow & 7)) & 7) << 4) + wi * 2) =
              (__bf16)p;
        }
      }
    }
    // PV + row-sum via ones-column
#pragma unroll
    for (int ks = 0; ks < 2; ++ks) {
      bf16x8_t vf[4];
#pragma unroll
      for (int e0 = 0; e0 < 4; ++e0) {
        int e = e0 * 16 + lo;
        int ch = ((ks * 4 + hi) ^ (((e >> 3) ^ e) & 7)) & 7;
        vf[e0] = *reinterpret_cast<const bf16x8_t*>((char*)Vt[cur] + e * 128 + (ch << 4));
      }
#pragma unroll
      for (int m = 0; m < 2; ++m) {
        int arow = w * 32 + m * 16 + lo;
        bf16x8_t pf = *reinterpret_cast<const bf16x8_t*>(
            (char*)Ps + arow * 128 + ((((ks * 4 + hi) ^ (arow & 7)) & 7) << 4));
#pragma unroll
        for (int e0 = 0; e0 < 4; ++e0)
          zacc[m][e0] = __builtin_amdgcn_mfma_f32_16x16x32_bf16(pf, vf[e0], zacc[m][e0], 0, 0, 0);
        lsum[m] = __builtin_amdgcn_mfma_f32_16x16x32_bf16(pf, vones, lsum[m], 0, 0, 0);
      }
    }
    if (!last) {
      asm volatile("s_waitcnt vmcnt(0)" ::: "memory");
      WRITE_V(cur ^ 1);
    }
    __syncthreads();
  }
  // epilogue: broadcast l from lane lo==0, normalize, store
#pragma unroll
  for (int m = 0; m < 2; ++m) {
#pragma unroll
    for (int r = 0; r < 4; ++r) {
      float lv = __shfl(lsum[m][r], l & 48);
      float inv = 1.0f / lv;
      size_t row = rowQ + m * 16 + hi * 4 + r;
#pragma unroll
      for (int e0 = 0; e0 < 4; ++e0)
        Z[row * 1024 + h * 64 + e0 * 16 + lo] = (__bf16)(zacc[m][e0][r] * inv);
    }
  }
#undef STAGE_K
#undef LOAD_V
#undef WRITE_V
}

// ---------------- launch ----------------

extern "C" void kernel_launch(void* const* d_in, const int* in_sizes, int n_in,
                              void* d_out, int out_size, void* d_ws, size_t ws_size,
                              hipStream_t stream) {
  const float* x  = (const float*)d_in[0];
  const float* wq = (const float*)d_in[1];
  const float* wk = (const float*)d_in[2];
  const float* wv = (const float*)d_in[3];
  const float* wo = (const float*)d_in[4];
  const float* bq = (const float*)d_in[5];
  const float* bk = (const float*)d_in[6];
  const float* bv = (const float*)d_in[7];
  const float* bo = (const float*)d_in[8];
  float* out = (float*)d_out;

  char* ws = (char*)d_ws;
  __bf16* Xb  = (__bf16*)(ws);                 //  8388608 B  [4096][1024]
  __bf16* WB1 = (__bf16*)(ws + 8388608);       //  6291456 B  [3072][1024]
  float*  B1  = (float*)(ws + 14680064);       //    12288 B  [3072]
  __bf16* WB2 = (__bf16*)(ws + 14692352);      //  2097152 B  [1024][1024]
  __bf16* QKV = (__bf16*)(ws + 16789504);      // 25165824 B  [4096][3072]
  __bf16* Zb  = Xb;                            // overlay: X dead after GEMM1

  k_cvt_x<<<4096, 256, 0, stream>>>(x, Xb, 1048576);
  k_packw1<<<dim3(16, 16, 3), 256, 0, stream>>>(wq, wk, wv, WB1);
  k_packw2<<<dim3(16, 16), 256, 0, stream>>>(wo, WB2);
  k_bias1<<<12, 256, 0, stream>>>(bq, bk, bv, B1);

  k_gemm<__bf16><<<dim3(24, 32), 256, 0, stream>>>(Xb, WB1, B1, QKV, 3072, 1024);
  k_attn<<<dim3(16, 32), 256, 0, stream>>>(QKV, Zb);
  k_gemm<float><<<dim3(8, 32), 256, 0, stream>>>(Zb, WB2, bo, out, 1024, 1024);
}

// Round 3
// 184.996 us; speedup vs baseline: 1.4985x; 1.4985x over previous
//
#include <hip/hip_runtime.h>

typedef float f32x4 __attribute__((ext_vector_type(4)));
typedef __bf16 bf16x8_t __attribute__((ext_vector_type(8)));
typedef __bf16 bf16x4_t __attribute__((ext_vector_type(4)));

#define GLOAD16(gptr, lptr)                                                        \
  __builtin_amdgcn_global_load_lds((const __attribute__((address_space(1))) void*)(gptr), \
                                   (__attribute__((address_space(3))) void*)(lptr), 16, 0, 0)

__device__ inline float fexp2(float x) {
  float r;
  asm("v_exp_f32 %0, %1" : "=v"(r) : "v"(x));
  return r;
}

// ---------------- prep kernels ----------------

__global__ __launch_bounds__(256) void k_cvt_x(const float* __restrict__ x,
                                               __bf16* __restrict__ xb, int n4) {
  int i = blockIdx.x * 256 + threadIdx.x;
  if (i >= n4) return;
  float4 a = reinterpret_cast<const float4*>(x)[i];
  bf16x4_t o;
  o[0] = (__bf16)a.x; o[1] = (__bf16)a.y; o[2] = (__bf16)a.z; o[3] = (__bf16)a.w;
  reinterpret_cast<bf16x4_t*>(xb)[i] = o;
}

// W_p[h][d][e] (fp32, [16][1024][64]) -> WB1[(p*1024 + h*64 + e)][d] bf16
__global__ __launch_bounds__(256) void k_packw1(const float* __restrict__ wq,
                                                const float* __restrict__ wk,
                                                const float* __restrict__ wv,
                                                __bf16* __restrict__ out) {
  __shared__ __bf16 tr[64][64];  // [e][dd]
  int p = blockIdx.z, h = blockIdx.y, dt = blockIdx.x;
  const float* W = (p == 0) ? wq : (p == 1) ? wk : wv;
  int t = threadIdx.x;
#pragma unroll
  for (int i = 0; i < 4; ++i) {
    int fl = i * 1024 + t * 4;    // d-major over 64x64 tile
    int dd = fl >> 6, e = fl & 63;
    float4 a = *reinterpret_cast<const float4*>(W + ((size_t)(h * 1024 + dt * 64 + dd) * 64 + e));
    tr[e + 0][dd] = (__bf16)a.x; tr[e + 1][dd] = (__bf16)a.y;
    tr[e + 2][dd] = (__bf16)a.z; tr[e + 3][dd] = (__bf16)a.w;
  }
  __syncthreads();
#pragma unroll
  for (int i = 0; i < 2; ++i) {
    int ch = i * 256 + t;         // 512 chunks of 8 elems
    int e = ch >> 3, c8 = ch & 7;
    *reinterpret_cast<bf16x8_t*>(out + ((size_t)(p * 1024 + h * 64 + e) * 1024 + dt * 64 + c8 * 8)) =
        *reinterpret_cast<const bf16x8_t*>(&tr[e][c8 * 8]);
  }
}

// W_O[h][e][n] (fp32, [16][64][1024]) -> WB2[n][h*64 + e] bf16
__global__ __launch_bounds__(256) void k_packw2(const float* __restrict__ wo,
                                                __bf16* __restrict__ out) {
  __shared__ __bf16 tr[64][64];  // [nn][e]
  int h = blockIdx.y, nt = blockIdx.x;
  int t = threadIdx.x;
#pragma unroll
  for (int i = 0; i < 4; ++i) {
    int fl = i * 1024 + t * 4;    // e-major
    int e = fl >> 6, nn = fl & 63;
    float4 a = *reinterpret_cast<const float4*>(wo + ((size_t)(h * 64 + e) * 1024 + nt * 64 + nn));
    tr[nn + 0][e] = (__bf16)a.x; tr[nn + 1][e] = (__bf16)a.y;
    tr[nn + 2][e] = (__bf16)a.z; tr[nn + 3][e] = (__bf16)a.w;
  }
  __syncthreads();
#pragma unroll
  for (int i = 0; i < 2; ++i) {
    int ch = i * 256 + t;
    int nn = ch >> 3, c8 = ch & 7;
    *reinterpret_cast<bf16x8_t*>(out + ((size_t)(nt * 64 + nn) * 1024 + h * 64 + c8 * 8)) =
        *reinterpret_cast<const bf16x8_t*>(&tr[nn][c8 * 8]);
  }
}

__global__ __launch_bounds__(256) void k_bias1(const float* __restrict__ bq,
                                               const float* __restrict__ bk,
                                               const float* __restrict__ bv,
                                               float* __restrict__ b1) {
  int n = blockIdx.x * 256 + threadIdx.x;
  if (n >= 3072) return;
  int p = n >> 10, he = n & 1023;
  const float* s = (p == 0) ? bq : (p == 1) ? bk : bv;
  b1[n] = s[he];
}

// ---------------- GEMM: C[M][N] = A[M][K] * Bt[N][K]^T + bias[N] ----------------
template <typename OutT>
__global__ __launch_bounds__(256) void k_gemm(const __bf16* __restrict__ A,
                                              const __bf16* __restrict__ Bt,
                                              const float* __restrict__ bias,
                                              OutT* __restrict__ C, int N, int K) {
  __shared__ __bf16 As[128 * 32];
  __shared__ __bf16 Bs[128 * 32];
  int t = threadIdx.x, l = t & 63;
  int lo = l & 15, hi = l >> 4;
  int w = t >> 6;
  int m0 = blockIdx.y * 128, n0 = blockIdx.x * 128;
  int wm = (w >> 1) * 64, wn = (w & 1) * 64;
  f32x4 acc[4][4] = {};
  for (int k0 = 0; k0 < K; k0 += 32) {
    __syncthreads();
#pragma unroll
    for (int it = 0; it < 2; ++it) {
      int idx = it * 256 + t;
      int row = idx >> 2, c = idx & 3;
      int cs = (c ^ (row & 3)) * 8;
      const __bf16* ga = A + (size_t)(m0 + row) * K + k0 + cs;
      const __bf16* gb = Bt + (size_t)(n0 + row) * K + k0 + cs;
      char* la = (char*)As + (it * 256 + (t & ~63)) * 16;
      char* lb = (char*)Bs + (it * 256 + (t & ~63)) * 16;
      GLOAD16(ga, la);
      GLOAD16(gb, lb);
    }
    __syncthreads();
    bf16x8_t af[4], bfr[4];
#pragma unroll
    for (int mi = 0; mi < 4; ++mi) {
      int row = wm + mi * 16 + lo;
      af[mi] = *reinterpret_cast<const bf16x8_t*>((char*)As + row * 64 + ((hi ^ (row & 3)) << 4));
    }
#pragma unroll
    for (int ni = 0; ni < 4; ++ni) {
      int row = wn + ni * 16 + lo;
      bfr[ni] = *reinterpret_cast<const bf16x8_t*>((char*)Bs + row * 64 + ((hi ^ (row & 3)) << 4));
    }
#pragma unroll
    for (int mi = 0; mi < 4; ++mi)
#pragma unroll
      for (int ni = 0; ni < 4; ++ni)
        acc[mi][ni] = __builtin_amdgcn_mfma_f32_16x16x32_bf16(af[mi], bfr[ni], acc[mi][ni], 0, 0, 0);
  }
#pragma unroll
  for (int ni = 0; ni < 4; ++ni) {
    int n = n0 + wn + ni * 16 + lo;
    float bv = bias[n];
#pragma unroll
    for (int mi = 0; mi < 4; ++mi) {
#pragma unroll
      for (int r = 0; r < 4; ++r) {
        int m = m0 + wm + mi * 16 + hi * 4 + r;
        C[(size_t)m * N + n] = (OutT)(acc[mi][ni][r] + bv);
      }
    }
  }
}

// ---------------- causal flash attention (v3) ----------------
// QBLK=64 (4 waves x 16 rows), KVBLK=64, double-buffered K/V, 1 barrier/tile.
// 1024 blocks, XCD-aware mapping: each XCD owns 4 heads (K+V = 2MB, L2-resident),
// long blocks dispatched first within each XCD for backfill.
__global__ __launch_bounds__(256, 4) void k_attn(const __bf16* __restrict__ QKV,
                                                 __bf16* __restrict__ Z) {
  __shared__ __bf16 Ks[2][64 * 64];  // row-swizzled: chunk ^= row&7
  __shared__ __bf16 Vt[2][64 * 64];  // [e][kv], chunk-swizzled
  __shared__ __bf16 Ps[64 * 64];     // row-swizzled, wave-private rows
  int t = threadIdx.x, l = t & 63, w = t >> 6;
  int lo = l & 15, hi = l >> 4;
  // bid -> (xcd, bh-local, qb): XCD g gets bh in [4g, 4g+4), long q-blocks first
  int bid = blockIdx.x;
  int xcdg = bid & 7, k = bid >> 3;
  int qbi = k & 31, bhl = k >> 5;
  int bh = xcdg * 4 + bhl;
  int b = bh >> 4, h = bh & 15;
  int q0 = (31 - qbi) * 64;
  int nt = 32 - qbi;
  const size_t rowQ = (size_t)(b * 2048 + q0 + w * 16);

  const __bf16* Kbase = QKV + (size_t)b * 2048 * 3072 + 1024 + h * 64;
  const __bf16* Vbase = QKV + (size_t)b * 2048 * 3072 + 2048 + h * 64;

  // Q fragments (k-chunks 0..31, 32..63)
  bf16x8_t qf[2];
  {
    const __bf16* qptr = QKV + (rowQ + lo) * 3072 + h * 64;
    qf[0] = *reinterpret_cast<const bf16x8_t*>(qptr + hi * 8);
    qf[1] = *reinterpret_cast<const bf16x8_t*>(qptr + 32 + hi * 8);
  }

  // ones B-fragment (col 0 = 1) for row-sum via MFMA
  bf16x8_t vones;
  {
    __bf16 v1 = (__bf16)((lo == 0) ? 1.0f : 0.0f);
#pragma unroll
    for (int j = 0; j < 8; ++j) vones[j] = v1;
  }

  f32x4 zacc[4] = {};
  f32x4 lsum = {};
  float mrow[4] = {-1e30f, -1e30f, -1e30f, -1e30f};

#define STAGE_K(buf, tile)                                                              \
  {                                                                                     \
    int kv0s = (tile) * 64;                                                             \
    _Pragma("unroll") for (int it = 0; it < 2; ++it) {                                  \
      int idx = it * 256 + t;                                                           \
      int row = idx >> 3, c = idx & 7;                                                  \
      const __bf16* gk = Kbase + (size_t)(kv0s + row) * 3072 + ((c ^ (row & 7)) * 8);   \
      GLOAD16(gk, (char*)Ks[buf] + (it * 256 + (t & ~63)) * 16);                        \
    }                                                                                   \
  }

#define LOAD_V(tile)                                                                    \
  {                                                                                     \
    _Pragma("unroll") for (int it = 0; it < 2; ++it) {                                  \
      int idx = it * 256 + t;                                                           \
      int kv = idx >> 3, c = idx & 7;                                                   \
      vr[it] = *reinterpret_cast<const bf16x8_t*>(                                      \
          Vbase + (size_t)((tile) * 64 + kv) * 3072 + c * 8);                           \
    }                                                                                   \
  }

#define WRITE_V(buf)                                                                    \
  {                                                                                     \
    _Pragma("unroll") for (int it = 0; it < 2; ++it) {                                  \
      int idx = it * 256 + t;                                                           \
      int kv = idx >> 3, c = idx & 7, kvc = kv >> 3, kvl = kv & 7;                      \
      _Pragma("unroll") for (int j = 0; j < 8; ++j) {                                   \
        int e = c * 8 + j;                                                              \
        *(__bf16*)((char*)Vt[buf] + e * 128 + (((kvc ^ c ^ j) & 7) << 4) + kvl * 2) =   \
            vr[it][j];                                                                  \
      }                                                                                 \
    }                                                                                   \
  }

  // prologue: stage tile 0 into buffer 0
  {
    bf16x8_t vr[2];
    STAGE_K(0, 0);
    LOAD_V(0);
    asm volatile("s_waitcnt vmcnt(0)" ::: "memory");
    WRITE_V(0);
  }
  __syncthreads();

  for (int tile = 0; tile < nt; ++tile) {
    int cur = tile & 1, kv0 = tile * 64;
    bool last = (tile == nt - 1);
    bf16x8_t vr[2];
    if (!last) {
      LOAD_V(tile + 1);
      __builtin_amdgcn_sched_barrier(0);
      STAGE_K(cur ^ 1, tile + 1);
      __builtin_amdgcn_sched_barrier(0);
    }
    // QK^T: sfr[cb], D[row=q(hi*4+r)][col=kv(lo)]
    f32x4 sfr[4] = {};
#pragma unroll
    for (int cb = 0; cb < 4; ++cb) {
      int krow = cb * 16 + lo;
      const char* kp = (const char*)Ks[cur] + krow * 128;
      bf16x8_t kf0 = *reinterpret_cast<const bf16x8_t*>(kp + ((hi ^ (krow & 7)) << 4));
      bf16x8_t kf1 = *reinterpret_cast<const bf16x8_t*>(kp + (((4 + hi) ^ (krow & 7)) << 4));
      sfr[cb] = __builtin_amdgcn_mfma_f32_16x16x32_bf16(qf[0], kf0, sfr[cb], 0, 0, 0);
      sfr[cb] = __builtin_amdgcn_mfma_f32_16x16x32_bf16(qf[1], kf1, sfr[cb], 0, 0, 0);
    }
    // V regs -> LDS for next tile (V loads were issued before K stage: vmcnt(2))
    if (!last) {
      asm volatile("s_waitcnt vmcnt(2)" ::: "memory");
      WRITE_V(cur ^ 1);
    }
    // softmax (exp2 domain; scale = 0.125*log2(e))
    {
      int qb = q0 + w * 16;
      bool msk = (kv0 + 63) > qb;
      float mt[4] = {-1e30f, -1e30f, -1e30f, -1e30f};
#pragma unroll
      for (int cb = 0; cb < 4; ++cb) {
#pragma unroll
        for (int r = 0; r < 4; ++r) {
          float v = sfr[cb][r] * 0.18033688f;
          if (msk && (kv0 + cb * 16 + lo > qb + hi * 4 + r)) v = -1e30f;
          sfr[cb][r] = v;
          mt[r] = fmaxf(mt[r], v);
        }
      }
#pragma unroll
      for (int r = 0; r < 4; ++r) {
        mt[r] = fmaxf(mt[r], __shfl_xor(mt[r], 8));
        mt[r] = fmaxf(mt[r], __shfl_xor(mt[r], 4));
        mt[r] = fmaxf(mt[r], __shfl_xor(mt[r], 2));
        mt[r] = fmaxf(mt[r], __shfl_xor(mt[r], 1));
        float mnew = fmaxf(mrow[r], mt[r]);
        float alpha = fexp2(mrow[r] - mnew);
        mrow[r] = mnew;
        lsum[r] *= alpha;
#pragma unroll
        for (int e0 = 0; e0 < 4; ++e0) zacc[e0][r] *= alpha;
      }
      // P = exp2(s - m) -> Ps (bf16, swizzled; wave-private rows)
#pragma unroll
      for (int cb = 0; cb < 4; ++cb) {
        int kvl = cb * 16 + lo, chp = kvl >> 3, wi = kvl & 7;
#pragma unroll
        for (int r = 0; r < 4; ++r) {
          float p = fexp2(sfr[cb][r] - mrow[r]);
          int prow = w * 16 + hi * 4 + r;
          *(__bf16*)((char*)Ps + prow * 128 + (((chp ^ (prow & 7)) & 7) << 4) + wi * 2) =
              (__bf16)p;
        }
      }
    }
    // PV + row-sum via ones-column
#pragma unroll
    for (int ks = 0; ks < 2; ++ks) {
      int arow = w * 16 + lo;
      bf16x8_t pf = *reinterpret_cast<const bf16x8_t*>(
          (char*)Ps + arow * 128 + ((((ks * 4 + hi) ^ (arow & 7)) & 7) << 4));
#pragma unroll
      for (int e0 = 0; e0 < 4; ++e0) {
        int e = e0 * 16 + lo;
        int ch = ((ks * 4 + hi) ^ (((e >> 3) ^ e) & 7)) & 7;
        bf16x8_t vf = *reinterpret_cast<const bf16x8_t*>((char*)Vt[cur] + e * 128 + (ch << 4));
        zacc[e0] = __builtin_amdgcn_mfma_f32_16x16x32_bf16(pf, vf, zacc[e0], 0, 0, 0);
      }
      lsum = __builtin_amdgcn_mfma_f32_16x16x32_bf16(pf, vones, lsum, 0, 0, 0);
    }
    __syncthreads();
  }
  // epilogue: broadcast l from lanes lo==0, normalize, store
#pragma unroll
  for (int r = 0; r < 4; ++r) {
    float lv = __shfl(lsum[r], l & 48);
    float inv = 1.0f / lv;
    size_t row = rowQ + hi * 4 + r;
#pragma unroll
    for (int e0 = 0; e0 < 4; ++e0)
      Z[row * 1024 + h * 64 + e0 * 16 + lo] = (__bf16)(zacc[e0][r] * inv);
  }
#undef STAGE_K
#undef LOAD_V
#undef WRITE_V
}

// ---------------- launch ----------------

extern "C" void kernel_launch(void* const* d_in, const int* in_sizes, int n_in,
                              void* d_out, int out_size, void* d_ws, size_t ws_size,
                              hipStream_t stream) {
  const float* x  = (const float*)d_in[0];
  const float* wq = (const float*)d_in[1];
  const float* wk = (const float*)d_in[2];
  const float* wv = (const float*)d_in[3];
  const float* wo = (const float*)d_in[4];
  const float* bq = (const float*)d_in[5];
  const float* bk = (const float*)d_in[6];
  const float* bv = (const float*)d_in[7];
  const float* bo = (const float*)d_in[8];
  float* out = (float*)d_out;

  char* ws = (char*)d_ws;
  __bf16* Xb  = (__bf16*)(ws);                 //  8388608 B  [4096][1024]
  __bf16* WB1 = (__bf16*)(ws + 8388608);       //  6291456 B  [3072][1024]
  float*  B1  = (float*)(ws + 14680064);       //    12288 B  [3072]
  __bf16* WB2 = (__bf16*)(ws + 14692352);      //  2097152 B  [1024][1024]
  __bf16* QKV = (__bf16*)(ws + 16789504);      // 25165824 B  [4096][3072]
  __bf16* Zb  = Xb;                            // overlay: X dead after GEMM1

  k_cvt_x<<<4096, 256, 0, stream>>>(x, Xb, 1048576);
  k_packw1<<<dim3(16, 16, 3), 256, 0, stream>>>(wq, wk, wv, WB1);
  k_packw2<<<dim3(16, 16), 256, 0, stream>>>(wo, WB2);
  k_bias1<<<12, 256, 0, stream>>>(bq, bk, bv, B1);

  k_gemm<__bf16><<<dim3(24, 32), 256, 0, stream>>>(Xb, WB1, B1, QKV, 3072, 1024);
  k_attn<<<1024, 256, 0, stream>>>(QKV, Zb);
  k_gemm<float><<<dim3(8, 32), 256, 0, stream>>>(Zb, WB2, bo, out, 1024, 1024);
}

// Round 4
// 151.765 us; speedup vs baseline: 1.8266x; 1.2190x over previous
//
#include <hip/hip_runtime.h>

typedef float f32x4 __attribute__((ext_vector_type(4)));
typedef __bf16 bf16x8_t __attribute__((ext_vector_type(8)));
typedef __bf16 bf16x4_t __attribute__((ext_vector_type(4)));

#define GLOAD16(gptr, lptr)                                                        \
  __builtin_amdgcn_global_load_lds((const __attribute__((address_space(1))) void*)(gptr), \
                                   (__attribute__((address_space(3))) void*)(lptr), 16, 0, 0)

__device__ inline float fexp2(float x) {
  float r;
  asm("v_exp_f32 %0, %1" : "=v"(r) : "v"(x));
  return r;
}

// ---------------- prep kernels ----------------

__global__ __launch_bounds__(256) void k_cvt_x(const float* __restrict__ x,
                                               __bf16* __restrict__ xb, int n4) {
  int i = blockIdx.x * 256 + threadIdx.x;
  if (i >= n4) return;
  float4 a = reinterpret_cast<const float4*>(x)[i];
  bf16x4_t o;
  o[0] = (__bf16)a.x; o[1] = (__bf16)a.y; o[2] = (__bf16)a.z; o[3] = (__bf16)a.w;
  reinterpret_cast<bf16x4_t*>(xb)[i] = o;
}

// W_p[h][d][e] (fp32, [16][1024][64]) -> WB1[(p*1024 + h*64 + e)][d] bf16
__global__ __launch_bounds__(256) void k_packw1(const float* __restrict__ wq,
                                                const float* __restrict__ wk,
                                                const float* __restrict__ wv,
                                                __bf16* __restrict__ out) {
  __shared__ __bf16 tr[64][64];  // [e][dd]
  int p = blockIdx.z, h = blockIdx.y, dt = blockIdx.x;
  const float* W = (p == 0) ? wq : (p == 1) ? wk : wv;
  int t = threadIdx.x;
#pragma unroll
  for (int i = 0; i < 4; ++i) {
    int fl = i * 1024 + t * 4;    // d-major over 64x64 tile
    int dd = fl >> 6, e = fl & 63;
    float4 a = *reinterpret_cast<const float4*>(W + ((size_t)(h * 1024 + dt * 64 + dd) * 64 + e));
    tr[e + 0][dd] = (__bf16)a.x; tr[e + 1][dd] = (__bf16)a.y;
    tr[e + 2][dd] = (__bf16)a.z; tr[e + 3][dd] = (__bf16)a.w;
  }
  __syncthreads();
#pragma unroll
  for (int i = 0; i < 2; ++i) {
    int ch = i * 256 + t;         // 512 chunks of 8 elems
    int e = ch >> 3, c8 = ch & 7;
    *reinterpret_cast<bf16x8_t*>(out + ((size_t)(p * 1024 + h * 64 + e) * 1024 + dt * 64 + c8 * 8)) =
        *reinterpret_cast<const bf16x8_t*>(&tr[e][c8 * 8]);
  }
}

// W_O[h][e][n] (fp32, [16][64][1024]) -> WB2[n][h*64 + e] bf16
__global__ __launch_bounds__(256) void k_packw2(const float* __restrict__ wo,
                                                __bf16* __restrict__ out) {
  __shared__ __bf16 tr[64][64];  // [nn][e]
  int h = blockIdx.y, nt = blockIdx.x;
  int t = threadIdx.x;
#pragma unroll
  for (int i = 0; i < 4; ++i) {
    int fl = i * 1024 + t * 4;    // e-major
    int e = fl >> 6, nn = fl & 63;
    float4 a = *reinterpret_cast<const float4*>(wo + ((size_t)(h * 64 + e) * 1024 + nt * 64 + nn));
    tr[nn + 0][e] = (__bf16)a.x; tr[nn + 1][e] = (__bf16)a.y;
    tr[nn + 2][e] = (__bf16)a.z; tr[nn + 3][e] = (__bf16)a.w;
  }
  __syncthreads();
#pragma unroll
  for (int i = 0; i < 2; ++i) {
    int ch = i * 256 + t;
    int nn = ch >> 3, c8 = ch & 7;
    *reinterpret_cast<bf16x8_t*>(out + ((size_t)(nt * 64 + nn) * 1024 + h * 64 + c8 * 8)) =
        *reinterpret_cast<const bf16x8_t*>(&tr[nn][c8 * 8]);
  }
}

__global__ __launch_bounds__(256) void k_bias1(const float* __restrict__ bq,
                                               const float* __restrict__ bk,
                                               const float* __restrict__ bv,
                                               float* __restrict__ b1) {
  int n = blockIdx.x * 256 + threadIdx.x;
  if (n >= 3072) return;
  int p = n >> 10, he = n & 1023;
  const float* s = (p == 0) ? bq : (p == 1) ? bk : bv;
  b1[n] = s[he];
}

// ---------------- GEMM: C[M][N] = A[M][K] * Bt[N][K]^T + bias[N] ----------------
template <typename OutT>
__global__ __launch_bounds__(256) void k_gemm(const __bf16* __restrict__ A,
                                              const __bf16* __restrict__ Bt,
                                              const float* __restrict__ bias,
                                              OutT* __restrict__ C, int N, int K) {
  __shared__ __bf16 As[128 * 32];
  __shared__ __bf16 Bs[128 * 32];
  int t = threadIdx.x, l = t & 63;
  int lo = l & 15, hi = l >> 4;
  int w = t >> 6;
  int m0 = blockIdx.y * 128, n0 = blockIdx.x * 128;
  int wm = (w >> 1) * 64, wn = (w & 1) * 64;
  f32x4 acc[4][4] = {};
  for (int k0 = 0; k0 < K; k0 += 32) {
    __syncthreads();
#pragma unroll
    for (int it = 0; it < 2; ++it) {
      int idx = it * 256 + t;
      int row = idx >> 2, c = idx & 3;
      int cs = (c ^ (row & 3)) * 8;
      const __bf16* ga = A + (size_t)(m0 + row) * K + k0 + cs;
      const __bf16* gb = Bt + (size_t)(n0 + row) * K + k0 + cs;
      char* la = (char*)As + (it * 256 + (t & ~63)) * 16;
      char* lb = (char*)Bs + (it * 256 + (t & ~63)) * 16;
      GLOAD16(ga, la);
      GLOAD16(gb, lb);
    }
    __syncthreads();
    bf16x8_t af[4], bfr[4];
#pragma unroll
    for (int mi = 0; mi < 4; ++mi) {
      int row = wm + mi * 16 + lo;
      af[mi] = *reinterpret_cast<const bf16x8_t*>((char*)As + row * 64 + ((hi ^ (row & 3)) << 4));
    }
#pragma unroll
    for (int ni = 0; ni < 4; ++ni) {
      int row = wn + ni * 16 + lo;
      bfr[ni] = *reinterpret_cast<const bf16x8_t*>((char*)Bs + row * 64 + ((hi ^ (row & 3)) << 4));
    }
#pragma unroll
    for (int mi = 0; mi < 4; ++mi)
#pragma unroll
      for (int ni = 0; ni < 4; ++ni)
        acc[mi][ni] = __builtin_amdgcn_mfma_f32_16x16x32_bf16(af[mi], bfr[ni], acc[mi][ni], 0, 0, 0);
  }
#pragma unroll
  for (int ni = 0; ni < 4; ++ni) {
    int n = n0 + wn + ni * 16 + lo;
    float bv = bias[n];
#pragma unroll
    for (int mi = 0; mi < 4; ++mi) {
#pragma unroll
      for (int r = 0; r < 4; ++r) {
        int m = m0 + wm + mi * 16 + hi * 4 + r;
        C[(size_t)m * N + n] = (OutT)(acc[mi][ni][r] + bv);
      }
    }
  }
}

// ---------------- causal flash attention (v4: paired q-tiles + swapped QK^T) ----
// Block (qi, bh) handles q-tiles {31-qi, qi}: exactly 33 tile-computes each.
// Swapped QK^T (mfma(K,Q)) puts S^T in regs: q-row = lane lo, kv in-lane.
// Grid 512 = 8 xcd * (16 qi * 4 bh-local); K+V for 4 heads = 2MB, L2-resident.
__global__ __launch_bounds__(256, 2) void k_attn(const __bf16* __restrict__ QKV,
                                                 __bf16* __restrict__ Z) {
  __shared__ __bf16 Ks[2][64 * 64];  // row-swizzled: chunk ^= row&7
  __shared__ __bf16 Vt[2][64 * 64];  // [e][kv], chunk-swizzled
  __shared__ __bf16 Ps[128 * 64];    // rows 0-63: high half, 64-127: low half
  int t = threadIdx.x, l = t & 63, w = t >> 6;
  int lo = l & 15, hi = l >> 4;
  int bid = blockIdx.x;
  int xcd = bid & 7, kk = bid >> 3;
  int qi = kk & 15, bhl = kk >> 4;
  int bh = xcd * 4 + bhl;
  int b = bh >> 4, h = bh & 15;
  const int qT[2] = {31 - qi, qi};  // half 0 = high (always active), half 1 = low
  int nt = qT[0] + 1;

  const __bf16* Kbase = QKV + (size_t)b * 2048 * 3072 + 1024 + h * 64;
  const __bf16* Vbase = QKV + (size_t)b * 2048 * 3072 + 2048 + h * 64;

  // Q fragments for both halves (B-operand layout: col=q=lo, k=d)
  bf16x8_t qf[2][2];
#pragma unroll
  for (int hf = 0; hf < 2; ++hf) {
    const __bf16* qptr = QKV + (size_t)(b * 2048 + qT[hf] * 64 + w * 16 + lo) * 3072 + h * 64;
    qf[hf][0] = *reinterpret_cast<const bf16x8_t*>(qptr + hi * 8);
    qf[hf][1] = *reinterpret_cast<const bf16x8_t*>(qptr + 32 + hi * 8);
  }

  // ones B-fragment (col 0 = 1) for row-sum via MFMA
  bf16x8_t vones;
  {
    __bf16 v1 = (__bf16)((lo == 0) ? 1.0f : 0.0f);
#pragma unroll
    for (int j = 0; j < 8; ++j) vones[j] = v1;
  }

  f32x4 zacc[2][4] = {};
  f32x4 lsum[2] = {};
  float mrow[2] = {-1e30f, -1e30f};
  const float SCALE = 0.18033688f;  // log2(e)/8

#define STAGE_K(buf, tile)                                                              \
  {                                                                                     \
    int kv0s = (tile) * 64;                                                             \
    _Pragma("unroll") for (int it = 0; it < 2; ++it) {                                  \
      int idx = it * 256 + t;                                                           \
      int row = idx >> 3, c = idx & 7;                                                  \
      const __bf16* gk = Kbase + (size_t)(kv0s + row) * 3072 + ((c ^ (row & 7)) * 8);   \
      GLOAD16(gk, (char*)Ks[buf] + (it * 256 + (t & ~63)) * 16);                        \
    }                                                                                   \
  }

#define LOAD_V(tile)                                                                    \
  {                                                                                     \
    _Pragma("unroll") for (int it = 0; it < 2; ++it) {                                  \
      int idx = it * 256 + t;                                                           \
      int kv = idx >> 3, c = idx & 7;                                                   \
      vr[it] = *reinterpret_cast<const bf16x8_t*>(                                      \
          Vbase + (size_t)((tile) * 64 + kv) * 3072 + c * 8);                           \
    }                                                                                   \
  }

#define WRITE_V(buf)                                                                    \
  {                                                                                     \
    _Pragma("unroll") for (int it = 0; it < 2; ++it) {                                  \
      int idx = it * 256 + t;                                                           \
      int kv = idx >> 3, c = idx & 7, kvc = kv >> 3, kvl = kv & 7;                      \
      _Pragma("unroll") for (int j = 0; j < 8; ++j) {                                   \
        int e = c * 8 + j;                                                              \
        *(__bf16*)((char*)Vt[buf] + e * 128 + (((kvc ^ c ^ j) & 7) << 4) + kvl * 2) =   \
            vr[it][j];                                                                  \
      }                                                                                 \
    }                                                                                   \
  }

  // softmax for one half; s holds S^T frags: s[cb][r] = S[q=lo][kv=cb*16+hi*4+r]
#define SOFTMAX_HALF(s, hf, kv0v, mskv)                                                 \
  {                                                                                     \
    int qabs = qT[hf] * 64 + w * 16 + lo;                                               \
    float mt = -1e30f;                                                                  \
    _Pragma("unroll") for (int cb = 0; cb < 4; ++cb)                                    \
    _Pragma("unroll") for (int r = 0; r < 4; ++r) {                                     \
      float v = s[cb][r] * SCALE;                                                       \
      if ((mskv) && ((kv0v) + cb * 16 + hi * 4 + r > qabs)) v = -1e30f;                 \
      s[cb][r] = v;                                                                     \
      mt = fmaxf(mt, v);                                                                \
    }                                                                                   \
    mt = fmaxf(mt, __shfl_xor(mt, 16));                                                 \
    mt = fmaxf(mt, __shfl_xor(mt, 32));                                                 \
    float mnew = fmaxf(mrow[hf], mt);                                                   \
    float alpha = fexp2(mrow[hf] - mnew);                                               \
    mrow[hf] = mnew;                                                                    \
    int prow = (hf) * 64 + w * 16 + lo;                                                 \
    char* prp = (char*)Ps + prow * 128 + (hi & 1) * 8;                                  \
    int rsw = prow & 7;                                                                 \
    _Pragma("unroll") for (int cb = 0; cb < 4; ++cb) {                                  \
      bf16x4_t pp;                                                                      \
      _Pragma("unroll") for (int r = 0; r < 4; ++r)                                     \
        pp[r] = (__bf16)fexp2(s[cb][r] - mnew);                                         \
      *reinterpret_cast<bf16x4_t*>(prp + (((cb * 2 + (hi >> 1)) ^ rsw) << 4)) = pp;     \
    }                                                                                   \
    _Pragma("unroll") for (int r = 0; r < 4; ++r) {                                     \
      float at = __shfl(alpha, hi * 4 + r);                                             \
      lsum[hf][r] *= at;                                                                \
      _Pragma("unroll") for (int e0 = 0; e0 < 4; ++e0) zacc[hf][e0][r] *= at;           \
    }                                                                                   \
  }

  // prologue: stage tile 0 into buffer 0
  {
    bf16x8_t vr[2];
    STAGE_K(0, 0);
    LOAD_V(0);
    WRITE_V(0);
  }
  __syncthreads();

  for (int tile = 0; tile < nt; ++tile) {
    int cur = tile & 1, kv0 = tile * 64;
    bool last = (tile == nt - 1);
    bool lowact = (tile <= qi);
    bf16x8_t vr[2];
    if (!last) {
      LOAD_V(tile + 1);
      STAGE_K(cur ^ 1, tile + 1);
      __builtin_amdgcn_sched_barrier(0);
    }
    // QK^T swapped: sfr[cb][r] = S[q=lo][kv=cb*16+hi*4+r]
    f32x4 sh[4] = {}, sl[4] = {};
    __builtin_amdgcn_s_setprio(1);
#pragma unroll
    for (int cb = 0; cb < 4; ++cb) {
      int krow = cb * 16 + lo;
      const char* kp = (const char*)Ks[cur] + krow * 128;
      bf16x8_t kf0 = *reinterpret_cast<const bf16x8_t*>(kp + ((hi ^ (krow & 7)) << 4));
      bf16x8_t kf1 = *reinterpret_cast<const bf16x8_t*>(kp + (((4 + hi) ^ (krow & 7)) << 4));
      sh[cb] = __builtin_amdgcn_mfma_f32_16x16x32_bf16(kf0, qf[0][0], sh[cb], 0, 0, 0);
      sh[cb] = __builtin_amdgcn_mfma_f32_16x16x32_bf16(kf1, qf[0][1], sh[cb], 0, 0, 0);
      if (lowact) {
        sl[cb] = __builtin_amdgcn_mfma_f32_16x16x32_bf16(kf0, qf[1][0], sl[cb], 0, 0, 0);
        sl[cb] = __builtin_amdgcn_mfma_f32_16x16x32_bf16(kf1, qf[1][1], sl[cb], 0, 0, 0);
      }
    }
    __builtin_amdgcn_s_setprio(0);
    // softmax both halves (mask only on the diagonal tile of each half)
    SOFTMAX_HALF(sh, 0, kv0, tile == qT[0]);
    if (lowact) SOFTMAX_HALF(sl, 1, kv0, tile == qT[1]);
    // PV + row-sum; V fragments shared between halves
    __builtin_amdgcn_s_setprio(1);
#pragma unroll
    for (int ks = 0; ks < 2; ++ks) {
      int arow = w * 16 + lo;
      bf16x8_t pfh = *reinterpret_cast<const bf16x8_t*>(
          (char*)Ps + arow * 128 + ((((ks * 4 + hi) ^ (arow & 7)) & 7) << 4));
      bf16x8_t pfl;
      if (lowact) {
        int arl = 64 + arow;
        pfl = *reinterpret_cast<const bf16x8_t*>(
            (char*)Ps + arl * 128 + ((((ks * 4 + hi) ^ (arl & 7)) & 7) << 4));
      }
#pragma unroll
      for (int e0 = 0; e0 < 4; ++e0) {
        int e = e0 * 16 + lo;
        int ch = ((ks * 4 + hi) ^ (((e >> 3) ^ e) & 7)) & 7;
        bf16x8_t vf = *reinterpret_cast<const bf16x8_t*>((char*)Vt[cur] + e * 128 + (ch << 4));
        zacc[0][e0] = __builtin_amdgcn_mfma_f32_16x16x32_bf16(pfh, vf, zacc[0][e0], 0, 0, 0);
        if (lowact)
          zacc[1][e0] = __builtin_amdgcn_mfma_f32_16x16x32_bf16(pfl, vf, zacc[1][e0], 0, 0, 0);
      }
      lsum[0] = __builtin_amdgcn_mfma_f32_16x16x32_bf16(pfh, vones, lsum[0], 0, 0, 0);
      if (lowact) lsum[1] = __builtin_amdgcn_mfma_f32_16x16x32_bf16(pfl, vones, lsum[1], 0, 0, 0);
    }
    __builtin_amdgcn_s_setprio(0);
    if (!last) WRITE_V(cur ^ 1);  // compiler waits vr loads here
    __syncthreads();
  }
  // epilogue: broadcast l from lanes lo==0, normalize, store both halves
#pragma unroll
  for (int hf = 0; hf < 2; ++hf) {
#pragma unroll
    for (int r = 0; r < 4; ++r) {
      float lv = __shfl(lsum[hf][r], l & 48);
      float inv = 1.0f / lv;
      size_t row = (size_t)(b * 2048 + qT[hf] * 64 + w * 16 + hi * 4 + r);
#pragma unroll
      for (int e0 = 0; e0 < 4; ++e0)
        Z[row * 1024 + h * 64 + e0 * 16 + lo] = (__bf16)(zacc[hf][e0][r] * inv);
    }
  }
#undef STAGE_K
#undef LOAD_V
#undef WRITE_V
#undef SOFTMAX_HALF
}

// ---------------- launch ----------------

extern "C" void kernel_launch(void* const* d_in, const int* in_sizes, int n_in,
                              void* d_out, int out_size, void* d_ws, size_t ws_size,
                              hipStream_t stream) {
  const float* x  = (const float*)d_in[0];
  const float* wq = (const float*)d_in[1];
  const float* wk = (const float*)d_in[2];
  const float* wv = (const float*)d_in[3];
  const float* wo = (const float*)d_in[4];
  const float* bq = (const float*)d_in[5];
  const float* bk = (const float*)d_in[6];
  const float* bv = (const float*)d_in[7];
  const float* bo = (const float*)d_in[8];
  float* out = (float*)d_out;

  char* ws = (char*)d_ws;
  __bf16* Xb  = (__bf16*)(ws);                 //  8388608 B  [4096][1024]
  __bf16* WB1 = (__bf16*)(ws + 8388608);       //  6291456 B  [3072][1024]
  float*  B1  = (float*)(ws + 14680064);       //    12288 B  [3072]
  __bf16* WB2 = (__bf16*)(ws + 14692352);      //  2097152 B  [1024][1024]
  __bf16* QKV = (__bf16*)(ws + 16789504);      // 25165824 B  [4096][3072]
  __bf16* Zb  = Xb;                            // overlay: X dead after GEMM1

  k_cvt_x<<<4096, 256, 0, stream>>>(x, Xb, 1048576);
  k_packw1<<<dim3(16, 16, 3), 256, 0, stream>>>(wq, wk, wv, WB1);
  k_packw2<<<dim3(16, 16), 256, 0, stream>>>(wo, WB2);
  k_bias1<<<12, 256, 0, stream>>>(bq, bk, bv, B1);

  k_gemm<__bf16><<<dim3(24, 32), 256, 0, stream>>>(Xb, WB1, B1, QKV, 3072, 1024);
  k_attn<<<512, 256, 0, stream>>>(QKV, Zb);
  k_gemm<float><<<dim3(8, 32), 256, 0, stream>>>(Zb, WB2, bo, out, 1024, 1024);
}